// Round 13
// baseline (324.209 us; speedup 1.0000x reference)
//
#include <hip/hip_runtime.h>
#include <hip/hip_bf16.h>

static constexpr int C  = 21;
static constexpr int H  = 384;
static constexpr int W  = 384;
static constexpr int HW = H * W;
static constexpr float NCLIQ = 5.0f;
static constexpr int CH = 3;            // channels per k_VF block (21 = 3*7)

typedef unsigned short u16;

// function-local constexpr taps: exp(-o^2/18), o=-6..6 — folds to immediates
#define GKDEF constexpr float gk[13] = { \
    0.13533528f, 0.24935222f, 0.41111229f, 0.60653066f, 0.80073740f, \
    0.94595947f, 1.00000000f, 0.94595947f, 0.80073740f, 0.60653066f, \
    0.41111229f, 0.24935222f, 0.13533528f }

__device__ __forceinline__ float bfu2f(u16 u) {
    return __uint_as_float(((unsigned)u) << 16);
}
__device__ __forceinline__ u16 f2bfu(float f) {
    unsigned x = __float_as_uint(f);
    return (u16)((x + 0x7FFF + ((x >> 16) & 1)) >> 16);   // RNE; inputs finite
}

// ---- prep: q/un planar + wtab (bf16) + msum + inverse norms + M1/M2 --------
__global__ __launch_bounds__(256)
void k_prep(const float* __restrict__ un, const float* __restrict__ rgb,
            const int* __restrict__ sp,
            const float* __restrict__ Wsp, const float* __restrict__ Wbi,
            const float* __restrict__ Cm,
            float* __restrict__ q, float* __restrict__ unp,
            u16* __restrict__ wtab, float* __restrict__ msum,
            float* __restrict__ inv_sp, float* __restrict__ inv_bn,
            float* __restrict__ M1, float* __restrict__ M2) {
    GKDEF;
    // fused k_mats: block 0, STRIDED over all 441 entries (R12 bug: only the
    // first 256 were computed, leaving M1/M2[256..440] as poison)
    if (blockIdx.x == 0) {
        for (int i = threadIdx.x; i < C * C; i += 256) {
            int c = i / C, k = i - c * C;
            float a1 = 0.f, a2 = 0.f;
            for (int j = 0; j < C; j++) {
                float cm = Cm[c * C + j];
                a1 += cm * Wsp[j * C + k];
                a2 += cm * Wbi[j * C + k];
            }
            M1[i] = a1;
            M2[i] = a2;
        }
    }

    int p = blockIdx.x * 256 + threadIdx.x;     // HW % 256 == 0
    int y = p / W, x = p - y * W;

    for (int c = 0; c < C; c++) {
        float v = un[p * C + c];
        q[c * HW + p] = v;
        unp[c * HW + p] = v;
    }

    // bilateral weights (bf16-rounded); denominator sums the SAME rounded
    // values so numerator/denominator stay consistent
    float r0 = rgb[p * 3 + 0];
    float g0 = rgb[p * 3 + 1];
    float b0 = rgb[p * 3 + 2];
    float s = 0.f;
    int t = 0;
    for (int dy = -2; dy <= 2; dy++) {
        for (int dx = -2; dx <= 2; dx++, t++) {
            int sy = y - dy, sx = x - dx;
            float wv = 0.f;
            if (sy >= 0 && sy < H && sx >= 0 && sx < W) {
                int o = sy * W + sx;
                float dr = r0 - rgb[o * 3 + 0];
                float dg = g0 - rgb[o * 3 + 1];
                float db = b0 - rgb[o * 3 + 2];
                wv = expf(-(float)(dy * dy + dx * dx) * (1.0f / 51200.0f)) *
                     expf(-(dr * dr + dg * dg + db * db) * (1.0f / 18.0f));
            }
            u16 wu = f2bfu(wv);
            wtab[(size_t)t * HW + p] = wu;
            s += bfu2f(wu);
        }
    }
    inv_bn[p] = 1.0f / s;    // s >= 1 (center tap)

    float fy = 0.f, fx = 0.f;
    for (int o = -6; o <= 6; o++) {
        if (y - o >= 0 && y - o < H) fy += gk[o + 6];
        if (x - o >= 0 && x - o < W) fx += gk[o + 6];
    }
    inv_sp[p] = 1.0f / (fy * fx);

    int vv = sp[x * W + y];   // sp_map is transposed: sp[x][y]
    msum[p] = (vv == 5 || vv == 37 || vv == 81 || vv == 150 || vv == 230) ? 1.0f : 0.0f;
}

// fused softmax + both 21x21 matmuls, pixel-parallel. M via uniform s_loads.
__global__ __launch_bounds__(256)
void k_ST(const float* __restrict__ q, const float* __restrict__ M1,
          const float* __restrict__ M2,
          u16* __restrict__ t1, u16* __restrict__ t2) {
    int p = blockIdx.x * 256 + threadIdx.x;
    float v[C];
    float mx = -1e30f;
#pragma unroll
    for (int c = 0; c < C; c++) {
        v[c] = q[c * HW + p];
        mx = fmaxf(mx, v[c]);
    }
    float s = 0.f;
#pragma unroll
    for (int c = 0; c < C; c++) {
        v[c] = expf(v[c] - mx);
        s += v[c];
    }
    float inv = 1.0f / s;
    float a1[C], a2[C];
#pragma unroll
    for (int c = 0; c < C; c++) { a1[c] = 0.f; a2[c] = 0.f; }
#pragma unroll
    for (int k = 0; k < C; k++) {
        float e = v[k];
#pragma unroll
        for (int c = 0; c < C; c++) {
            a1[c] += M1[c * C + k] * e;   // uniform index -> s_load
            a2[c] += M2[c * C + k] * e;
        }
    }
#pragma unroll
    for (int c = 0; c < C; c++) {
        t1[c * HW + p] = f2bfu(a1[c] * inv);
        t2[c * HW + p] = f2bfu(a2[c] * inv);
    }
}

// fused separable blur (LDS-tiled) + bilateral + update.
// CH=3 channels per block; 128x8 tile; wtab cached in registers across channels.
__global__ __launch_bounds__(256)
void k_VF(const u16* __restrict__ t1, const u16* __restrict__ t2,
          const u16* __restrict__ wtab, const float* __restrict__ msum,
          const float* __restrict__ inv_sp, const float* __restrict__ inv_bn,
          const float* __restrict__ unp,
          const float* __restrict__ loww, const float* __restrict__ highw,
          float* __restrict__ q) {
    GKDEF;
    __shared__ u16   A[CH * 20 * 144];   // t1 halo tiles, bf16
    __shared__ float B[CH * 8 * 144];    // blurV outputs
    int c0 = blockIdx.z * CH;
    int x0 = blockIdx.x * 128;
    int y0 = blockIdx.y * 8;

    // ---- stage A (zero-padded), ushort4 ----
    for (int i = threadIdx.x; i < CH * 20 * 36; i += 256) {
        int ch = i / 720, rem = i - ch * 720;
        int r = rem / 36, q4 = rem - r * 36;
        int gy = y0 - 6 + r;
        int gx = x0 - 8 + q4 * 4;     // 4-aligned
        const u16* t1p = t1 + (size_t)(c0 + ch) * HW;
        ushort4 u;
        if (gy < 0 || gy >= H) {
            u.x = u.y = u.z = u.w = 0;
        } else if (gx >= 0 && gx + 3 < W) {
            u = *(const ushort4*)(t1p + gy * W + gx);
        } else {
            u16 e[4];
            for (int j = 0; j < 4; j++) {
                int xx = gx + j;
                e[j] = (xx >= 0 && xx < W) ? t1p[gy * W + xx] : (u16)0;
            }
            u.x = e[0]; u.y = e[1]; u.z = e[2]; u.w = e[3];
        }
        *(ushort4*)(A + (ch * 20 + r) * 144 + q4 * 4) = u;
    }
    __syncthreads();

    // ---- blurV: B[ch][r][col] = sum_d gk[d] * A[ch][r+d][col] ----
    for (int i = threadIdx.x; i < CH * 8 * 144; i += 256) {
        int ch = i / 1152, rem = i - ch * 1152;
        int r = rem / 144, col = rem - r * 144;
        float a = 0.f;
        for (int d = 0; d < 13; d++)
            a += gk[d] * bfu2f(A[(ch * 20 + r + d) * 144 + col]);
        B[i] = a;
    }
    __syncthreads();

    // ---- per-thread: 4 consecutive x of one row, all CH channels ----
    int row = threadIdx.x >> 5;            // 0..7
    int xq  = (threadIdx.x & 31) * 4;      // 0..124
    int y   = y0 + row;
    int x4  = x0 + xq;
    int p4  = y * W + x4;

    // channel-invariant per-pixel data: load ONCE
    ushort4 wv[25];
#pragma unroll
    for (int t = 0; t < 25; t++)
        wv[t] = *(const ushort4*)(wtab + (size_t)t * HW + p4);
    float4 msv = *(const float4*)(msum + p4);
    float4 isv = *(const float4*)(inv_sp + p4);
    float4 ibv = *(const float4*)(inv_bn + p4);
    float msa[4] = {msv.x, msv.y, msv.z, msv.w};
    float isa[4] = {isv.x, isv.y, isv.z, isv.w};
    float iba[4] = {ibv.x, ibv.y, ibv.z, ibv.w};
    float hw_ = highw[0];

    for (int ch = 0; ch < CH; ch++) {
        int c = c0 + ch;

        // horizontal 13-tap from LDS B
        float bw[16];
        for (int i = 0; i < 16; i++) bw[i] = B[(ch * 8 + row) * 144 + xq + 2 + i];
        float sp_[4];
        for (int j = 0; j < 4; j++) {
            float a = 0.f;
            for (int t = 0; t < 13; t++) a += gk[t] * bw[j + t];
            sp_[j] = a;
        }

        // bilateral over t2 (bf16; OOB taps carry weight 0)
        float bi[4] = {0.f, 0.f, 0.f, 0.f};
        const u16* t2p = t2 + (size_t)c * HW;
        int t = 0;
        for (int dy = -2; dy <= 2; dy++) {
            int sy = min(max(y - dy, 0), H - 1);    // clamped; OOB rows weight 0
            const u16* rowp = t2p + sy * W;
            float r[12];
            for (int i = 0; i < 3; i++) {
                int bx = x4 - 4 + 4 * i;
                int bc = min(max(bx, 0), W - 4);    // clamped; OOB cols weight 0
                ushort4 u = *(const ushort4*)(rowp + bc);
                r[4 * i + 0] = bfu2f(u.x); r[4 * i + 1] = bfu2f(u.y);
                r[4 * i + 2] = bfu2f(u.z); r[4 * i + 3] = bfu2f(u.w);
            }
            for (int dx = -2; dx <= 2; dx++, t++) {
                bi[0] += bfu2f(wv[t].x) * r[0 - dx + 4];
                bi[1] += bfu2f(wv[t].y) * r[1 - dx + 4];
                bi[2] += bfu2f(wv[t].z) * r[2 - dx + 4];
                bi[3] += bfu2f(wv[t].w) * r[3 - dx + 4];
            }
        }

        // update: q = un - pairwise + superpixel closed form
        float lc = loww[c];
        float4 unv = *(const float4*)(unp + (size_t)c * HW + p4);
        float* qp = q + (size_t)c * HW + p4;
        float4 qo4 = *(const float4*)qp;
        float qoa[4] = {qo4.x, qo4.y, qo4.z, qo4.w};
        float una[4] = {unv.x, unv.y, unv.z, unv.w};
        float outv[4];
        for (int j = 0; j < 4; j++) {
            float pw = sp_[j] * isa[j] + bi[j] * iba[j];
            float qo = qoa[j];
            float ft = (msa[j] * qo + (NCLIQ - msa[j])) / qo;
            float su = lc * ft + hw_ * (1.0f - ft);
            outv[j] = una[j] - pw + su;
        }
        float4 res; res.x = outv[0]; res.y = outv[1]; res.z = outv[2]; res.w = outv[3];
        *(float4*)qp = res;
    }
}

// final transpose: q (C,H,W) -> out (H,W,C), LDS-staged
__global__ __launch_bounds__(256)
void k_store(const float* __restrict__ q, float* __restrict__ out) {
    __shared__ float l[256 * C];
    int p0 = blockIdx.x * 256;
    for (int c = 0; c < C; c++)
        l[threadIdx.x * C + c] = q[c * HW + p0 + threadIdx.x];
    __syncthreads();
    float* dst = out + (size_t)p0 * C;
    for (int i = threadIdx.x; i < 256 * C; i += 256) dst[i] = l[i];
}

// ---- launch -----------------------------------------------------------------

extern "C" void kernel_launch(void* const* d_in, const int* in_sizes, int n_in,
                              void* d_out, int out_size, void* d_ws, size_t ws_size,
                              hipStream_t stream) {
    const float* un    = (const float*)d_in[0];
    const float* rgb   = (const float*)d_in[1];
    const int*   sp    = (const int*)d_in[2];
    const float* Wsp   = (const float*)d_in[3];
    const float* Wbi   = (const float*)d_in[4];
    const float* Cm    = (const float*)d_in[5];
    const float* loww  = (const float*)d_in[6];
    const float* highw = (const float*)d_in[7];
    float* out = (float*)d_out;

    // ws layout ~46.5 MB (ws_size ~256 MiB per harness fill WRITE_SIZE)
    float* ws    = (float*)d_ws;
    float* q     = ws;                            // C*HW fp32
    float* unp   = q   + (size_t)C * HW;          // C*HW fp32
    float* msum  = unp + (size_t)C * HW;          // HW
    float* isp   = msum + HW;                     // HW
    float* ibn   = isp + HW;                      // HW
    float* M1    = ibn + HW;                      // C*C
    float* M2    = M1 + C * C;                    // C*C
    u16*   t1    = (u16*)(M2 + C * C + 6);        // C*HW bf16 (8B-aligned)
    u16*   t2    = t1 + (size_t)C * HW;           // C*HW bf16
    u16*   wtab  = t2 + (size_t)C * HW;           // 25*HW bf16

    dim3 blk(256);
    dim3 gpix(HW / 256);                 // 576
    dim3 gVF(W / 128, H / 8, C / CH);    // 3 x 48 x 7

    k_prep<<<gpix, blk, 0, stream>>>(un, rgb, sp, Wsp, Wbi, Cm,
                                     q, unp, wtab, msum, isp, ibn, M1, M2);

    for (int it = 0; it < 5; it++) {
        k_ST<<<gpix, blk, 0, stream>>>(q, M1, M2, t1, t2);
        k_VF<<<gVF, blk, 0, stream>>>(t1, t2, wtab, msum, isp, ibn,
                                      unp, loww, highw, q);
    }
    k_store<<<gpix, blk, 0, stream>>>(q, out);
}

// Round 14
// 288.025 us; speedup vs baseline: 1.1256x; 1.1256x over previous
//
#include <hip/hip_runtime.h>
#include <hip/hip_bf16.h>

static constexpr int C  = 21;
static constexpr int H  = 384;
static constexpr int W  = 384;
static constexpr int HW = H * W;
static constexpr float NCLIQ = 5.0f;

typedef unsigned short u16;

// function-local constexpr taps: exp(-o^2/18), o=-6..6 — folds to immediates
#define GKDEF constexpr float gk[13] = { \
    0.13533528f, 0.24935222f, 0.41111229f, 0.60653066f, 0.80073740f, \
    0.94595947f, 1.00000000f, 0.94595947f, 0.80073740f, 0.60653066f, \
    0.41111229f, 0.24935222f, 0.13533528f }

__device__ __forceinline__ float bfu2f(u16 u) {
    return __uint_as_float(((unsigned)u) << 16);
}
__device__ __forceinline__ u16 f2bfu(float f) {
    unsigned x = __float_as_uint(f);
    return (u16)((x + 0x7FFF + ((x >> 16) & 1)) >> 16);   // RNE; inputs finite
}

// ---- prep: q/un planar + wtab (bf16) + msum + inverse norms + M1/M2 --------
__global__ __launch_bounds__(256)
void k_prep(const float* __restrict__ un, const float* __restrict__ rgb,
            const int* __restrict__ sp,
            const float* __restrict__ Wsp, const float* __restrict__ Wbi,
            const float* __restrict__ Cm,
            float* __restrict__ q, float* __restrict__ unp,
            u16* __restrict__ wtab, float* __restrict__ msum,
            float* __restrict__ inv_sp, float* __restrict__ inv_bn,
            float* __restrict__ M1, float* __restrict__ M2) {
    GKDEF;
    // fused k_mats: block 0, strided over all 441 entries
    if (blockIdx.x == 0) {
        for (int i = threadIdx.x; i < C * C; i += 256) {
            int c = i / C, k = i - c * C;
            float a1 = 0.f, a2 = 0.f;
            for (int j = 0; j < C; j++) {
                float cm = Cm[c * C + j];
                a1 += cm * Wsp[j * C + k];
                a2 += cm * Wbi[j * C + k];
            }
            M1[i] = a1;
            M2[i] = a2;
        }
    }

    int p = blockIdx.x * 256 + threadIdx.x;     // HW % 256 == 0
    int y = p / W, x = p - y * W;

    for (int c = 0; c < C; c++) {
        float v = un[p * C + c];
        q[c * HW + p] = v;
        unp[c * HW + p] = v;
    }

    // bilateral weights (bf16-rounded); denominator sums the SAME rounded
    // values so numerator/denominator stay consistent
    float r0 = rgb[p * 3 + 0];
    float g0 = rgb[p * 3 + 1];
    float b0 = rgb[p * 3 + 2];
    float s = 0.f;
    int t = 0;
    for (int dy = -2; dy <= 2; dy++) {
        for (int dx = -2; dx <= 2; dx++, t++) {
            int sy = y - dy, sx = x - dx;
            float wv = 0.f;
            if (sy >= 0 && sy < H && sx >= 0 && sx < W) {
                int o = sy * W + sx;
                float dr = r0 - rgb[o * 3 + 0];
                float dg = g0 - rgb[o * 3 + 1];
                float db = b0 - rgb[o * 3 + 2];
                wv = expf(-(float)(dy * dy + dx * dx) * (1.0f / 51200.0f)) *
                     expf(-(dr * dr + dg * dg + db * db) * (1.0f / 18.0f));
            }
            u16 wu = f2bfu(wv);
            wtab[(size_t)t * HW + p] = wu;
            s += bfu2f(wu);
        }
    }
    inv_bn[p] = 1.0f / s;    // s >= 1 (center tap)

    float fy = 0.f, fx = 0.f;
    for (int o = -6; o <= 6; o++) {
        if (y - o >= 0 && y - o < H) fy += gk[o + 6];
        if (x - o >= 0 && x - o < W) fx += gk[o + 6];
    }
    inv_sp[p] = 1.0f / (fy * fx);

    int vv = sp[x * W + y];   // sp_map is transposed: sp[x][y]
    msum[p] = (vv == 5 || vv == 37 || vv == 81 || vv == 150 || vv == 230) ? 1.0f : 0.0f;
}

// fused softmax + both 21x21 matmuls, pixel-parallel. M via uniform s_loads.
// XCD-swizzled: XCD k owns pixel rows [48k, 48k+48).
__global__ __launch_bounds__(256)
void k_ST(const float* __restrict__ q, const float* __restrict__ M1,
          const float* __restrict__ M2,
          u16* __restrict__ t1, u16* __restrict__ t2) {
    int bid = blockIdx.x;                  // grid 576
    int chunk = (bid & 7) * 72 + (bid >> 3);
    int p = chunk * 256 + threadIdx.x;
    float v[C];
    float mx = -1e30f;
#pragma unroll
    for (int c = 0; c < C; c++) {
        v[c] = q[c * HW + p];
        mx = fmaxf(mx, v[c]);
    }
    float s = 0.f;
#pragma unroll
    for (int c = 0; c < C; c++) {
        v[c] = expf(v[c] - mx);
        s += v[c];
    }
    float inv = 1.0f / s;
    float a1[C], a2[C];
#pragma unroll
    for (int c = 0; c < C; c++) { a1[c] = 0.f; a2[c] = 0.f; }
#pragma unroll
    for (int k = 0; k < C; k++) {
        float e = v[k];
#pragma unroll
        for (int c = 0; c < C; c++) {
            a1[c] += M1[c * C + k] * e;   // uniform index -> s_load
            a2[c] += M2[c * C + k] * e;
        }
    }
#pragma unroll
    for (int c = 0; c < C; c++) {
        t1[c * HW + p] = f2bfu(a1[c] * inv);
        t2[c * HW + p] = f2bfu(a2[c] * inv);
    }
}

// fused separable blur (LDS-tiled) + bilateral + update. R11 shape (1 ch/block,
// fp32 A) with XCD swizzle: all 21 channel-blocks of a pixel stripe land on
// one XCD so wtab/t2 slices stay in that XCD's 4MB L2 (vs 155MB LLC re-reads).
__global__ __launch_bounds__(256)
void k_VF(const u16* __restrict__ t1, const u16* __restrict__ t2,
          const u16* __restrict__ wtab, const float* __restrict__ msum,
          const float* __restrict__ inv_sp, const float* __restrict__ inv_bn,
          const float* __restrict__ unp,
          const float* __restrict__ loww, const float* __restrict__ highw,
          float* __restrict__ q) {
    GKDEF;
    __shared__ float A[20 * 144];   // t1 halo tile (fp32)
    __shared__ float B[8 * 144];    // blurV output
    // decode: bid = xcd + 8*(c + 21*(xt + 3*ytl)); XCD k owns y-tiles [6k,6k+6)
    int bid = blockIdx.x;                  // grid 3024
    int xcd = bid & 7;
    int idx = bid >> 3;                    // 0..377
    int c   = idx % 21;
    int rem = idx / 21;                    // 0..17
    int xt  = rem % 3;
    int ytl = rem / 3;                     // 0..5
    int x0 = xt * 128;
    int y0 = (xcd * 6 + ytl) * 8;
    const u16* t1p = t1 + (size_t)c * HW;

    // ---- stage A (zero-padded), bf16 -> fp32 ----
    for (int i = threadIdx.x; i < 20 * 36; i += 256) {
        int r = i / 36, q4 = i - r * 36;
        int gy = y0 - 6 + r;
        int gx = x0 - 8 + q4 * 4;     // 4-aligned
        float4 v;
        if (gy < 0 || gy >= H) {
            v.x = v.y = v.z = v.w = 0.f;
        } else if (gx >= 0 && gx + 3 < W) {
            ushort4 u = *(const ushort4*)(t1p + gy * W + gx);
            v.x = bfu2f(u.x); v.y = bfu2f(u.y); v.z = bfu2f(u.z); v.w = bfu2f(u.w);
        } else {
            float e[4];
            for (int j = 0; j < 4; j++) {
                int xx = gx + j;
                e[j] = (xx >= 0 && xx < W) ? bfu2f(t1p[gy * W + xx]) : 0.f;
            }
            v.x = e[0]; v.y = e[1]; v.z = e[2]; v.w = e[3];
        }
        *(float4*)(A + r * 144 + q4 * 4) = v;
    }
    __syncthreads();

    // ---- blurV: B[r][col] = sum_d gk[d] * A[r+d][col] ----
    for (int i = threadIdx.x; i < 8 * 144; i += 256) {
        int r = i / 144, col = i - r * 144;
        float a = 0.f;
        for (int d = 0; d < 13; d++) a += gk[d] * A[(r + d) * 144 + col];
        B[i] = a;
    }
    __syncthreads();

    // ---- per-thread: 4 consecutive x of one row ----
    int row = threadIdx.x >> 5;            // 0..7
    int xq  = (threadIdx.x & 31) * 4;      // 0..124
    int y   = y0 + row;
    int x4  = x0 + xq;
    int p4  = y * W + x4;

    // horizontal 13-tap from LDS B
    float bw[16];
    for (int i = 0; i < 16; i++) bw[i] = B[row * 144 + xq + 2 + i];
    float sp_[4];
    for (int j = 0; j < 4; j++) {
        float a = 0.f;
        for (int t = 0; t < 13; t++) a += gk[t] * bw[j + t];
        sp_[j] = a;
    }

    // bilateral over t2 (bf16; OOB taps carry weight 0)
    float bi[4] = {0.f, 0.f, 0.f, 0.f};
    const u16* t2p = t2 + (size_t)c * HW;
    int t = 0;
    for (int dy = -2; dy <= 2; dy++) {
        int sy = min(max(y - dy, 0), H - 1);    // clamped; OOB rows weight 0
        const u16* rowp = t2p + sy * W;
        float r[12];
        for (int i = 0; i < 3; i++) {
            int bx = x4 - 4 + 4 * i;
            int bc = min(max(bx, 0), W - 4);    // clamped; OOB cols weight 0
            ushort4 u = *(const ushort4*)(rowp + bc);
            r[4 * i + 0] = bfu2f(u.x); r[4 * i + 1] = bfu2f(u.y);
            r[4 * i + 2] = bfu2f(u.z); r[4 * i + 3] = bfu2f(u.w);
        }
        for (int dx = -2; dx <= 2; dx++, t++) {
            ushort4 wu = *(const ushort4*)(wtab + (size_t)t * HW + p4);
            bi[0] += bfu2f(wu.x) * r[0 - dx + 4];
            bi[1] += bfu2f(wu.y) * r[1 - dx + 4];
            bi[2] += bfu2f(wu.z) * r[2 - dx + 4];
            bi[3] += bfu2f(wu.w) * r[3 - dx + 4];
        }
    }

    // update: q = un - pairwise + superpixel closed form
    float lc = loww[c], hw_ = highw[0];
    float4 msv = *(const float4*)(msum + p4);
    float4 isv = *(const float4*)(inv_sp + p4);
    float4 ibv = *(const float4*)(inv_bn + p4);
    float4 unv = *(const float4*)(unp + (size_t)c * HW + p4);
    float* qp = q + (size_t)c * HW + p4;
    float4 qo4 = *(const float4*)qp;
    float msa[4] = {msv.x, msv.y, msv.z, msv.w};
    float isa[4] = {isv.x, isv.y, isv.z, isv.w};
    float iba[4] = {ibv.x, ibv.y, ibv.z, ibv.w};
    float qoa[4] = {qo4.x, qo4.y, qo4.z, qo4.w};
    float una[4] = {unv.x, unv.y, unv.z, unv.w};
    float outv[4];
    for (int j = 0; j < 4; j++) {
        float pw = sp_[j] * isa[j] + bi[j] * iba[j];
        float qo = qoa[j];
        float ft = (msa[j] * qo + (NCLIQ - msa[j])) / qo;
        float su = lc * ft + hw_ * (1.0f - ft);
        outv[j] = una[j] - pw + su;
    }
    float4 res; res.x = outv[0]; res.y = outv[1]; res.z = outv[2]; res.w = outv[3];
    *(float4*)qp = res;
}

// final transpose: q (C,H,W) -> out (H,W,C), LDS-staged, XCD-swizzled
__global__ __launch_bounds__(256)
void k_store(const float* __restrict__ q, float* __restrict__ out) {
    __shared__ float l[256 * C];
    int bid = blockIdx.x;                  // grid 576
    int chunk = (bid & 7) * 72 + (bid >> 3);
    int p0 = chunk * 256;
    for (int c = 0; c < C; c++)
        l[threadIdx.x * C + c] = q[c * HW + p0 + threadIdx.x];
    __syncthreads();
    float* dst = out + (size_t)p0 * C;
    for (int i = threadIdx.x; i < 256 * C; i += 256) dst[i] = l[i];
}

// ---- launch -----------------------------------------------------------------

extern "C" void kernel_launch(void* const* d_in, const int* in_sizes, int n_in,
                              void* d_out, int out_size, void* d_ws, size_t ws_size,
                              hipStream_t stream) {
    const float* un    = (const float*)d_in[0];
    const float* rgb   = (const float*)d_in[1];
    const int*   sp    = (const int*)d_in[2];
    const float* Wsp   = (const float*)d_in[3];
    const float* Wbi   = (const float*)d_in[4];
    const float* Cm    = (const float*)d_in[5];
    const float* loww  = (const float*)d_in[6];
    const float* highw = (const float*)d_in[7];
    float* out = (float*)d_out;

    // ws layout ~46.5 MB
    float* ws    = (float*)d_ws;
    float* q     = ws;                            // C*HW fp32
    float* unp   = q   + (size_t)C * HW;          // C*HW fp32
    float* msum  = unp + (size_t)C * HW;          // HW
    float* isp   = msum + HW;                     // HW
    float* ibn   = isp + HW;                      // HW
    float* M1    = ibn + HW;                      // C*C
    float* M2    = M1 + C * C;                    // C*C
    u16*   t1    = (u16*)(M2 + C * C + 6);        // C*HW bf16 (8B-aligned)
    u16*   t2    = t1 + (size_t)C * HW;           // C*HW bf16
    u16*   wtab  = t2 + (size_t)C * HW;           // 25*HW bf16

    dim3 blk(256);
    dim3 gpix(HW / 256);                 // 576
    dim3 gVF(3 * 48 * C);                // 3024, 1-D swizzled

    k_prep<<<gpix, blk, 0, stream>>>(un, rgb, sp, Wsp, Wbi, Cm,
                                     q, unp, wtab, msum, isp, ibn, M1, M2);

    for (int it = 0; it < 5; it++) {
        k_ST<<<gpix, blk, 0, stream>>>(q, M1, M2, t1, t2);
        k_VF<<<gVF, blk, 0, stream>>>(t1, t2, wtab, msum, isp, ibn,
                                      unp, loww, highw, q);
    }
    k_store<<<gpix, blk, 0, stream>>>(q, out);
}